// Round 1
// baseline (394.103 us; speedup 1.0000x reference)
//
#include <hip/hip_runtime.h>

typedef unsigned short u16;
typedef __attribute__((ext_vector_type(8))) short short8;
typedef __attribute__((ext_vector_type(8))) _Float16 h8;
typedef __attribute__((ext_vector_type(4))) float f32x4;

// ---- bf16 <-> f32 bit helpers ----
__device__ __forceinline__ float b2f(u16 u) {
    return __uint_as_float(((unsigned int)u) << 16);
}
__device__ __forceinline__ u16 f2b(float f) {
    unsigned int x = __float_as_uint(f);
    return (u16)((x + 0x7FFFu + ((x >> 16) & 1u)) >> 16);   // RNE
}
__device__ __forceinline__ float ldf(const void* p, size_t i, bool f32) {
    return f32 ? ((const float*)p)[i] : b2f(((const u16*)p)[i]);
}
__device__ __forceinline__ void stf(void* p, size_t i, bool f32, float v) {
    if (f32) ((float*)p)[i] = v; else ((u16*)p)[i] = f2b(v);
}
// raw v_exp_f32: computes 2^x in one trans op (no log2e pre-mul)
__device__ __forceinline__ float ex2(float x) {
    float r; asm("v_exp_f32 %0, %1" : "=v"(r) : "v"(x)); return r;
}

// async global -> LDS, 16 B per lane (dest = wave-uniform base + lane*16)
__device__ __forceinline__ void ldsld16(const void* g, void* l) {
    __builtin_amdgcn_global_load_lds(
        (const __attribute__((address_space(1))) unsigned int*)g,
        (__attribute__((address_space(3))) unsigned int*)l, 16, 0, 0);
}

// ---------------------------------------------------------------------------
// dtype probe (evidence: flag=1/f32 on this harness; keep robust)
// ---------------------------------------------------------------------------
__global__ void detect_f32(const u16* __restrict__ q, int* __restrict__ flag) {
    __shared__ int cw, cz;
    if (threadIdx.x == 0) { cw = 0; cz = 0; }
    __syncthreads();
    int w = 0, z = 0;
    for (int i = threadIdx.x; i < 4096; i += 256) {
        u16 u = q[i];
        int e = (u >> 7) & 0xFF;
        if (e >= 0xC8) w++;
        if (((i & 1) == 0) && u == 0) z++;
    }
    atomicAdd(&cw, w); atomicAdd(&cz, z);
    __syncthreads();
    if (threadIdx.x == 0) *flag = (cw > 8 || cz > 1024) ? 1 : 0;
}

// ---------------------------------------------------------------------------
// convert 3 tensors -> bf16 ws in one launch. grid (n/2048, 1, 3)
// ---------------------------------------------------------------------------
__global__ __launch_bounds__(256) void cvt3(
    const void* __restrict__ s0, const void* __restrict__ s1,
    const void* __restrict__ s2, u16* __restrict__ d0, u16* __restrict__ d1,
    u16* __restrict__ d2, int n, const int* __restrict__ flag)
{
    const bool f32 = (*flag) != 0;
    const int z = blockIdx.z;
    const void* src = (z == 0) ? s0 : (z == 1) ? s1 : s2;
    u16* dst = (z == 0) ? d0 : (z == 1) ? d1 : d2;
    const int i = (blockIdx.x * 256 + threadIdx.x) * 8;
    if (i >= n) return;
    short8 o;
    if (f32) {
        const float4* s = (const float4*)((const float*)src + i);
        float4 v0 = s[0], v1 = s[1];
        o[0] = (short)f2b(v0.x); o[1] = (short)f2b(v0.y);
        o[2] = (short)f2b(v0.z); o[3] = (short)f2b(v0.w);
        o[4] = (short)f2b(v1.x); o[5] = (short)f2b(v1.y);
        o[6] = (short)f2b(v1.z); o[7] = (short)f2b(v1.w);
    } else {
        o = *(const short8*)((const u16*)src + i);
    }
    *(short8*)(dst + i) = o;
}

// ---------------------------------------------------------------------------
// precompute diff = exp(sigmoid(qde)) -> f16. h-independent: computed once
// on 8.4M elems instead of 3 trans/elem on 67M in the attention hot loop.
// ---------------------------------------------------------------------------
__global__ __launch_bounds__(256) void prep_diff(
    const void* __restrict__ qde, _Float16* __restrict__ diff, int n,
    const int* __restrict__ flag)
{
    const bool f32 = (*flag) != 0;
    const int i = (blockIdx.x * 256 + threadIdx.x) * 8;
    if (i >= n) return;
    float x[8];
    if (f32) {
        const float4* s = (const float4*)((const float*)qde + i);
        float4 v0 = s[0], v1 = s[1];
        x[0] = v0.x; x[1] = v0.y; x[2] = v0.z; x[3] = v0.w;
        x[4] = v1.x; x[5] = v1.y; x[6] = v1.z; x[7] = v1.w;
    } else {
        short8 v8 = *(const short8*)((const u16*)qde + i);
        #pragma unroll
        for (int j = 0; j < 8; ++j) x[j] = b2f((u16)v8[j]);
    }
    h8 o;
    #pragma unroll
    for (int j = 0; j < 8; ++j) {
        float sig = __builtin_amdgcn_rcpf(1.f + __expf(-x[j]));
        o[j] = (_Float16)__expf(sig);
    }
    *(h8*)(diff + i) = o;
}

// ---------------------------------------------------------------------------
// MFMA GEMM core (m97-style): C[m,n] = sum_k A[m,k]*W[n,k] + bias[n]
// ---------------------------------------------------------------------------
#define BM 128
#define BN 128
#define BK 32

__device__ __forceinline__ void gemm_body(
    const u16* __restrict__ A, const u16* __restrict__ W,
    const void* __restrict__ bias, void* __restrict__ dst,
    bool f32, int mode, int bm, int bn, int M, int N, int K)
{
    __shared__ u16 As[BM * BK];   // 8 KB
    __shared__ u16 Bs[BN * BK];   // 8 KB
    const int t = threadIdx.x;
    const int w = t >> 6, l = t & 63, lq = l & 15, quad = l >> 4;
    const int wr = (w >> 1) * 64, wc = (w & 1) * 64;

    const int whalf = (w & 1) * 64;
    const u16* gsrc = (w < 2) ? A : W;
    const int  gbase = (w < 2) ? bm : bn;
    u16* lbase = (w < 2) ? As : Bs;

    f32x4 acc[4][4] = {};

    for (int k0 = 0; k0 < K; k0 += BK) {
        __syncthreads();
        #pragma unroll
        for (int c = 0; c < 4; ++c) {
            const int row = whalf + c * 16 + (l >> 2);
            ldsld16(gsrc + (size_t)(gbase + row) * K + k0 + (l & 3) * 8,
                    lbase + row * BK + (l & 3) * 8);
        }
        asm volatile("s_waitcnt vmcnt(0)" ::: "memory");
        __syncthreads();
        short8 af[4], bf[4];
        #pragma unroll
        for (int i = 0; i < 4; ++i)
            af[i] = *(const short8*)&As[(wr + i * 16 + lq) * BK + quad * 8];
        #pragma unroll
        for (int j = 0; j < 4; ++j)
            bf[j] = *(const short8*)&Bs[(wc + j * 16 + lq) * BK + quad * 8];
        #pragma unroll
        for (int i = 0; i < 4; ++i)
            #pragma unroll
            for (int j = 0; j < 4; ++j)
                acc[i][j] = __builtin_amdgcn_mfma_f32_16x16x32_bf16(
                    af[i], bf[j], acc[i][j], 0, 0, 0);
    }

    #pragma unroll
    for (int j = 0; j < 4; ++j) {
        const int n = bn + wc + j * 16 + lq;
        const float bb = ldf(bias, n, f32);
        #pragma unroll
        for (int i = 0; i < 4; ++i) {
            #pragma unroll
            for (int r = 0; r < 4; ++r) {
                const int m = bm + wr + i * 16 + quad * 4 + r;
                const float vout = acc[i][j][r] + bb;
                if (mode == 0) {
                    const int b = m >> 9, s = m & 511, hh = n >> 6, df = n & 63;
                    ((u16*)dst)[((((size_t)b * 8 + hh) * 512 + s) << 6) + df] = f2b(vout);
                } else if (mode == 2) {
                    const int b = m >> 9, s = m & 511, hh = n >> 6, df = n & 63;
                    ((u16*)dst)[((((size_t)b * 8 + hh) * 64 + df) << 9) + s] = f2b(vout);
                } else {
                    stf(dst, (size_t)m * N + n, f32, vout);
                }
            }
        }
    }
}

__global__ __launch_bounds__(256) void proj3(
    const u16* __restrict__ cq, const u16* __restrict__ ck,
    const u16* __restrict__ cv, const u16* __restrict__ cWk,
    const u16* __restrict__ cWv, const void* __restrict__ bk,
    const void* __restrict__ bv, u16* __restrict__ qh, u16* __restrict__ kh,
    u16* __restrict__ vt, const int* __restrict__ flag, int M, int N, int K)
{
    const int z = blockIdx.z;
    const u16* A = (z == 0) ? cq : (z == 1) ? ck : cv;
    const u16* W = (z < 2) ? cWk : cWv;
    const void* bias = (z < 2) ? bk : bv;
    void* dst = (z == 0) ? (void*)qh : (z == 1) ? (void*)kh : (void*)vt;
    gemm_body(A, W, bias, dst, (*flag) != 0, (z < 2) ? 0 : 2,
              blockIdx.y * BM, blockIdx.x * BN, M, N, K);
}

__global__ __launch_bounds__(256) void gemm_out(
    const u16* __restrict__ A, const u16* __restrict__ W,
    const void* __restrict__ bias, void* __restrict__ dst,
    const int* __restrict__ flag, int M, int N, int K)
{
    gemm_body(A, W, bias, dst, (*flag) != 0, 1,
              blockIdx.y * BM, blockIdx.x * BN, M, N, K);
}

// ---------------------------------------------------------------------------
// Fused AKT attention. Grid 8192 (XCD-swizzled), 512 thr.
// Phase 1 stores scores pre-scaled by 0.125*log2(e) -> all exps are raw
// v_exp_f32. Phase 2 uses precomputed f16 diff (3 trans ops removed/elem).
// ---------------------------------------------------------------------------
#define QT  16
#define SRS 568   // u16 units; row = 1136 B (16B-aligned)
#define PRS 584

__global__ __launch_bounds__(512) void akt_attn(
    const u16* __restrict__ qh, const u16* __restrict__ kh,
    const u16* __restrict__ vt, const _Float16* __restrict__ diff,
    const void* __restrict__ gammas, const int* __restrict__ zero_pad,
    const int* __restrict__ flag, u16* __restrict__ attn)
{
    __shared__ _Float16 s_h[QT * SRS];   // 18176 B (reused as f32 partials ph3)
    __shared__ u16      p_lds[QT * PRS]; // 18688 B

    const int blk = blockIdx.x;
    const int h = blk & 7;               // XCD pin: (b,h) fixed per XCD
    const int i0 = blk >> 3;
    const int qt = i0 & 31;
    const int b = i0 >> 5;

    const int q0 = qt * QT;
    const int t = threadIdx.x, w = t >> 6, l = t & 63;
    const int lq = l & 15, quad = l >> 4;
    const bool f32 = (*flag) != 0;
    const size_t bh = ((size_t)b * 8 + h) * 512;
    const int qmax = q0 + QT - 1;

    // ---------------- phase 1: scores = (qh @ kh^T) * 0.125*log2e -> f16 ----
    {
        const u16* qb = qh + (bh + q0) * 64;
        short8 af0 = *(const short8*)(qb + lq * 64 +      quad * 8);
        short8 af1 = *(const short8*)(qb + lq * 64 + 32 + quad * 8);
        const u16* kb = kh + bh * 64;
        const int KT = (q0 + QT + 127) >> 7;
        int n0 = w * 16;
        bool act = (n0 <= qmax);
        short8 bf0, bf1;
        if (act) {
            bf0 = *(const short8*)(kb + (size_t)(n0 + lq) * 64 +      quad * 8);
            bf1 = *(const short8*)(kb + (size_t)(n0 + lq) * 64 + 32 + quad * 8);
        }
        for (int kt = 0; kt < KT; ++kt) {
            const int n0n = (kt + 1) * 128 + w * 16;
            const bool actn = (kt + 1 < KT) && (n0n <= qmax);
            short8 nb0, nb1;
            if (actn) {
                nb0 = *(const short8*)(kb + (size_t)(n0n + lq) * 64 +      quad * 8);
                nb1 = *(const short8*)(kb + (size_t)(n0n + lq) * 64 + 32 + quad * 8);
            }
            if (act) {
                f32x4 acc = {0.f, 0.f, 0.f, 0.f};
                acc = __builtin_amdgcn_mfma_f32_16x16x32_bf16(af0, bf0, acc, 0, 0, 0);
                acc = __builtin_amdgcn_mfma_f32_16x16x32_bf16(af1, bf1, acc, 0, 0, 0);
                const int cm = n0 + lq + 8 * (n0 >> 6);
                #pragma unroll
                for (int r = 0; r < 4; ++r)
                    s_h[(quad * 4 + r) * SRS + cm] =
                        (_Float16)(acc[r] * 0.180336880f);  // 0.125*log2e
            }
            bf0 = nb0; bf1 = nb1; act = actn; n0 = n0n;
        }
    }
    __syncthreads();

    // ---------------- phase 2: per-row rescore (one wave : two rows) --------
    {
        const float g = ldf(gammas, h, f32);
        const float gl2 = -log1pf(expf(g)) * 1.4426950408889634f; // gamma*log2e
        const int zp = zero_pad[0];
        const int c0 = l * 8;
        #pragma unroll
        for (int rr = 0; rr < 2; ++rr) {
            const int row = w * 2 + rr;
            const int q = q0 + row;
            // precomputed diff prefetch FIRST (f16, 16 B/lane)
            const size_t qoff = ((size_t)b * 512 + q) * 512 + c0;
            h8 dv = *(const h8*)(diff + qoff);
            // aligned vector score load (16 B); values already in log2 domain
            h8 sv16 = *(const h8*)(s_h + row * SRS + c0 + 8 * (l >> 3));
            float sv[8], cs[8];
            float run = 0.f;
            #pragma unroll
            for (int j = 0; j < 8; ++j) {
                float s = (c0 + j <= q) ? (float)sv16[j] : -1e30f;
                sv[j] = s;
                float p = ex2(s);                 // softmax #1 numerator
                run += p; cs[j] = run;
            }
            float incl = run;
            #pragma unroll
            for (int o = 1; o < 64; o <<= 1) {
                float u = __shfl_up(incl, o, 64);
                if (l >= o) incl += u;
            }
            const float ls   = __shfl(incl, 63, 64);
            const float inv1 = __builtin_amdgcn_rcpf(ls);
            const float t0   = ls - incl + run;   // ls - exclusive_prefix
            const float qf   = (float)(q - c0);
            // decay rescore + softmax #2 (disttot == 1 identically)
            float f8[8]; float lf = 0.f;
            #pragma unroll
            for (int j = 0; j < 8; ++j) {
                float suf  = t0 - cs[j];          // suffix sum (unnormalized)
                float pos  = qf - (float)j;
                float m    = fmaxf(suf * pos, 0.f) * inv1;
                float dist = __builtin_amdgcn_sqrtf(m);
                // gamma<0 -> arg<=0 -> eff<=1; only low clamp binds:
                // eff>=1e-5  <=>  arg >= log2(1e-5)
                float a    = fmaxf(dist * gl2 * (float)dv[j], -16.609640474f);
                float eff  = ex2(a);
                // masked lanes: sv=-1e30, eff>=1e-5 -> s2<=-1e25 -> f=0
                float f    = ex2(sv[j] * eff);
                f8[j] = f; lf += f;
            }
            #pragma unroll
            for (int o = 32; o > 0; o >>= 1) lf += __shfl_xor(lf, o, 64);
            float inv2 = __builtin_amdgcn_rcpf(lf);
            if (zp && q == 0) inv2 = 0.f;
            short8 pb;
            #pragma unroll
            for (int j = 0; j < 8; ++j) pb[j] = (short)f2b(f8[j] * inv2);
            *(short8*)(p_lds + row * PRS + c0 + 8 * (l >> 3)) = pb;
        }
    }
    __syncthreads();

    // ---------------- phase 3: O = P @ V, all 8 waves (k-halves) ------------
    {
        const int g = w & 3;                 // output 16-col group
        const int half = w >> 2;             // k-chunk parity
        const int KS = (qmax >> 5) + 1;
        const u16* vb = vt + ((size_t)(b * 8 + h) * 64 + g * 16 + lq) * 512;
        const u16* prow = p_lds + lq * PRS;
        f32x4 oacc = {0.f, 0.f, 0.f, 0.f};
        for (int ks = half; ks < KS; ks += 2) {
            const int kb2 = ks * 32 + quad * 8;
            short8 pa = *(const short8*)(prow + kb2 + 8 * (kb2 >> 6));
            short8 vv = *(const short8*)(vb + kb2);
            oacc = __builtin_amdgcn_mfma_f32_16x16x32_bf16(pa, vv, oacc, 0, 0, 0);
        }
        float* opart = (float*)s_h;          // reuse score LDS (post-barrier)
        if (half == 1) {
            #pragma unroll
            for (int r = 0; r < 4; ++r)
                opart[(g * 16 + quad * 4 + r) * 17 + lq] = oacc[r];
        }
        __syncthreads();
        if (half == 0) {
            const size_t ob = ((size_t)b * 512 + q0 + quad * 4) * 512 + h * 64 + g * 16 + lq;
            #pragma unroll
            for (int r = 0; r < 4; ++r)
                attn[ob + (size_t)r * 512] =
                    f2b(oacc[r] + opart[(g * 16 + quad * 4 + r) * 17 + lq]);
        }
    }
}

// ---------------------------------------------------------------------------
extern "C" void kernel_launch(void* const* d_in, const int* in_sizes, int n_in,
                              void* d_out, int out_size, void* d_ws, size_t ws_size,
                              hipStream_t stream) {
    const void* q   = d_in[0];
    const void* k   = d_in[1];
    const void* v   = d_in[2];
    // d_in[3] = mask (tril) == (k<=q), unused
    const int*  zp  = (const int*)d_in[4];
    const void* qde = d_in[5];
    const void* Wk  = d_in[6];
    const void* bk  = d_in[7];
    const void* Wv  = d_in[8];
    const void* bv  = d_in[9];
    const void* Wo  = d_in[10];
    const void* bo  = d_in[11];
    const void* gam = d_in[12];

    const int M = 32 * 512, N = 512, K = 512;
    const int NBIG = M * K;        // 8388608
    const int NW = 512 * 512;      // 262144

    char* ws = (char*)d_ws;
    int* flag = (int*)ws;
    const size_t SZB = (size_t)NBIG * 2;   // 16.8 MB
    const size_t SZW = (size_t)NW * 2;     // 0.5 MB
    u16* cWk  = (u16*)(ws + 1024);
    u16* cWv  = (u16*)(ws + 1024 + SZW);
    u16* cWo  = (u16*)(ws + 1024 + 2 * SZW);
    u16* cq   = (u16*)(ws + 1024 + 3 * SZW);
    u16* ck   = (u16*)(ws + 1024 + 3 * SZW + SZB);
    u16* cv   = (u16*)(ws + 1024 + 3 * SZW + 2 * SZB);
    u16* qh   = (u16*)(ws + 1024 + 3 * SZW + 3 * SZB);
    u16* kh   = (u16*)(ws + 1024 + 3 * SZW + 4 * SZB);
    u16* vt   = (u16*)(ws + 1024 + 3 * SZW + 5 * SZB);   // [B,H,64,S]
    u16* attn = (u16*)(ws + 1024 + 3 * SZW + 6 * SZB);   // [B,S,512]

    detect_f32<<<1, 256, 0, stream>>>((const u16*)q, flag);
    cvt3<<<dim3(NW / 2048, 1, 3), 256, 0, stream>>>(Wk, Wv, Wo, cWk, cWv, cWo, NW, flag);
    cvt3<<<dim3(NBIG / 2048, 1, 3), 256, 0, stream>>>(q, k, v, cq, ck, cv, NBIG, flag);
    proj3<<<dim3(N / BN, M / BM, 3), 256, 0, stream>>>(
        cq, ck, cv, cWk, cWv, bk, bv, qh, kh, vt, flag, M, N, K);
    // cq dead after proj3 -> reuse its slot for f16 diff = exp(sigmoid(qde))
    _Float16* diffb = (_Float16*)cq;
    prep_diff<<<dim3(NBIG / 2048), 256, 0, stream>>>(qde, diffb, NBIG, flag);
    akt_attn<<<8192, 512, 0, stream>>>(qh, kh, vt, diffb, gam, zp, flag, attn);
    gemm_out<<<dim3(N / BN, M / BM), 256, 0, stream>>>(attn, cWo, bo, d_out, flag, M, N, K);
}

// Round 3
// 383.740 us; speedup vs baseline: 1.0270x; 1.0270x over previous
//
#include <hip/hip_runtime.h>

typedef unsigned short u16;
typedef __attribute__((ext_vector_type(8))) short short8;
typedef __attribute__((ext_vector_type(8))) _Float16 h8;
typedef __attribute__((ext_vector_type(4))) float f32x4;

// ---- bf16 <-> f32 bit helpers ----
__device__ __forceinline__ float b2f(u16 u) {
    return __uint_as_float(((unsigned int)u) << 16);
}
__device__ __forceinline__ u16 f2b(float f) {
    unsigned int x = __float_as_uint(f);
    return (u16)((x + 0x7FFFu + ((x >> 16) & 1u)) >> 16);   // RNE
}
__device__ __forceinline__ float ldf(const void* p, size_t i, bool f32) {
    return f32 ? ((const float*)p)[i] : b2f(((const u16*)p)[i]);
}
__device__ __forceinline__ void stf(void* p, size_t i, bool f32, float v) {
    if (f32) ((float*)p)[i] = v; else ((u16*)p)[i] = f2b(v);
}
// raw v_exp_f32: computes 2^x in one trans op (no log2e pre-mul)
__device__ __forceinline__ float ex2(float x) {
    float r; asm("v_exp_f32 %0, %1" : "=v"(r) : "v"(x)); return r;
}

// async global -> LDS, 16 B per lane (dest = wave-uniform base + lane*16)
__device__ __forceinline__ void ldsld16(const void* g, void* l) {
    __builtin_amdgcn_global_load_lds(
        (const __attribute__((address_space(1))) unsigned int*)g,
        (__attribute__((address_space(3))) unsigned int*)l, 16, 0, 0);
}

// ---------------------------------------------------------------------------
// dtype probe (evidence: flag=1/f32 on this harness; keep robust)
// ---------------------------------------------------------------------------
__global__ void detect_f32(const u16* __restrict__ q, int* __restrict__ flag) {
    __shared__ int cw, cz;
    if (threadIdx.x == 0) { cw = 0; cz = 0; }
    __syncthreads();
    int w = 0, z = 0;
    for (int i = threadIdx.x; i < 4096; i += 256) {
        u16 u = q[i];
        int e = (u >> 7) & 0xFF;
        if (e >= 0xC8) w++;
        if (((i & 1) == 0) && u == 0) z++;
    }
    atomicAdd(&cw, w); atomicAdd(&cz, z);
    __syncthreads();
    if (threadIdx.x == 0) *flag = (cw > 8 || cz > 1024) ? 1 : 0;
}

// ---------------------------------------------------------------------------
// convert 3 tensors -> bf16 ws in one launch. grid (n/2048, 1, 3)
// ---------------------------------------------------------------------------
__global__ __launch_bounds__(256) void cvt3(
    const void* __restrict__ s0, const void* __restrict__ s1,
    const void* __restrict__ s2, u16* __restrict__ d0, u16* __restrict__ d1,
    u16* __restrict__ d2, int n, const int* __restrict__ flag)
{
    const bool f32 = (*flag) != 0;
    const int z = blockIdx.z;
    const void* src = (z == 0) ? s0 : (z == 1) ? s1 : s2;
    u16* dst = (z == 0) ? d0 : (z == 1) ? d1 : d2;
    const int i = (blockIdx.x * 256 + threadIdx.x) * 8;
    if (i >= n) return;
    short8 o;
    if (f32) {
        const float4* s = (const float4*)((const float*)src + i);
        float4 v0 = s[0], v1 = s[1];
        o[0] = (short)f2b(v0.x); o[1] = (short)f2b(v0.y);
        o[2] = (short)f2b(v0.z); o[3] = (short)f2b(v0.w);
        o[4] = (short)f2b(v1.x); o[5] = (short)f2b(v1.y);
        o[6] = (short)f2b(v1.z); o[7] = (short)f2b(v1.w);
    } else {
        o = *(const short8*)((const u16*)src + i);
    }
    *(short8*)(dst + i) = o;
}

// ---------------------------------------------------------------------------
// precompute diff = exp(sigmoid(qde)) -> f16. h-independent: computed once
// on 8.4M elems instead of 3 trans/elem on 67M in the attention hot loop.
// ---------------------------------------------------------------------------
__global__ __launch_bounds__(256) void prep_diff(
    const void* __restrict__ qde, _Float16* __restrict__ diff, int n,
    const int* __restrict__ flag)
{
    const bool f32 = (*flag) != 0;
    const int i = (blockIdx.x * 256 + threadIdx.x) * 8;
    if (i >= n) return;
    float x[8];
    if (f32) {
        const float4* s = (const float4*)((const float*)qde + i);
        float4 v0 = s[0], v1 = s[1];
        x[0] = v0.x; x[1] = v0.y; x[2] = v0.z; x[3] = v0.w;
        x[4] = v1.x; x[5] = v1.y; x[6] = v1.z; x[7] = v1.w;
    } else {
        short8 v8 = *(const short8*)((const u16*)qde + i);
        #pragma unroll
        for (int j = 0; j < 8; ++j) x[j] = b2f((u16)v8[j]);
    }
    h8 o;
    #pragma unroll
    for (int j = 0; j < 8; ++j) {
        float sig = __builtin_amdgcn_rcpf(1.f + __expf(-x[j]));
        o[j] = (_Float16)__expf(sig);
    }
    *(h8*)(diff + i) = o;
}

// ---------------------------------------------------------------------------
// MFMA GEMM core (m97-style): C[m,n] = sum_k A[m,k]*W[n,k] + bias[n]
// mode 0: bf16 head-split; mode 2: f16 head-split^T (V path); mode 1: flat
// ---------------------------------------------------------------------------
#define BM 128
#define BN 128
#define BK 32

__device__ __forceinline__ void gemm_body(
    const u16* __restrict__ A, const u16* __restrict__ W,
    const void* __restrict__ bias, void* __restrict__ dst,
    bool f32, int mode, int bm, int bn, int M, int N, int K)
{
    __shared__ u16 As[BM * BK];   // 8 KB
    __shared__ u16 Bs[BN * BK];   // 8 KB
    const int t = threadIdx.x;
    const int w = t >> 6, l = t & 63, lq = l & 15, quad = l >> 4;
    const int wr = (w >> 1) * 64, wc = (w & 1) * 64;

    const int whalf = (w & 1) * 64;
    const u16* gsrc = (w < 2) ? A : W;
    const int  gbase = (w < 2) ? bm : bn;
    u16* lbase = (w < 2) ? As : Bs;

    f32x4 acc[4][4] = {};

    for (int k0 = 0; k0 < K; k0 += BK) {
        __syncthreads();
        #pragma unroll
        for (int c = 0; c < 4; ++c) {
            const int row = whalf + c * 16 + (l >> 2);
            ldsld16(gsrc + (size_t)(gbase + row) * K + k0 + (l & 3) * 8,
                    lbase + row * BK + (l & 3) * 8);
        }
        asm volatile("s_waitcnt vmcnt(0)" ::: "memory");
        __syncthreads();
        short8 af[4], bf[4];
        #pragma unroll
        for (int i = 0; i < 4; ++i)
            af[i] = *(const short8*)&As[(wr + i * 16 + lq) * BK + quad * 8];
        #pragma unroll
        for (int j = 0; j < 4; ++j)
            bf[j] = *(const short8*)&Bs[(wc + j * 16 + lq) * BK + quad * 8];
        #pragma unroll
        for (int i = 0; i < 4; ++i)
            #pragma unroll
            for (int j = 0; j < 4; ++j)
                acc[i][j] = __builtin_amdgcn_mfma_f32_16x16x32_bf16(
                    af[i], bf[j], acc[i][j], 0, 0, 0);
    }

    #pragma unroll
    for (int j = 0; j < 4; ++j) {
        const int n = bn + wc + j * 16 + lq;
        const float bb = ldf(bias, n, f32);
        #pragma unroll
        for (int i = 0; i < 4; ++i) {
            #pragma unroll
            for (int r = 0; r < 4; ++r) {
                const int m = bm + wr + i * 16 + quad * 4 + r;
                const float vout = acc[i][j][r] + bb;
                if (mode == 0) {
                    const int b = m >> 9, s = m & 511, hh = n >> 6, df = n & 63;
                    ((u16*)dst)[((((size_t)b * 8 + hh) * 512 + s) << 6) + df] = f2b(vout);
                } else if (mode == 2) {
                    const int b = m >> 9, s = m & 511, hh = n >> 6, df = n & 63;
                    _Float16 hv = (_Float16)vout;   // V stored f16 for phase-3 f16 MFMA
                    ((u16*)dst)[((((size_t)b * 8 + hh) * 64 + df) << 9) + s] = *(const u16*)&hv;
                } else {
                    stf(dst, (size_t)m * N + n, f32, vout);
                }
            }
        }
    }
}

__global__ __launch_bounds__(256) void proj3(
    const u16* __restrict__ cq, const u16* __restrict__ ck,
    const u16* __restrict__ cv, const u16* __restrict__ cWk,
    const u16* __restrict__ cWv, const void* __restrict__ bk,
    const void* __restrict__ bv, u16* __restrict__ qh, u16* __restrict__ kh,
    u16* __restrict__ vt, const int* __restrict__ flag, int M, int N, int K)
{
    const int z = blockIdx.z;
    const u16* A = (z == 0) ? cq : (z == 1) ? ck : cv;
    const u16* W = (z < 2) ? cWk : cWv;
    const void* bias = (z < 2) ? bk : bv;
    void* dst = (z == 0) ? (void*)qh : (z == 1) ? (void*)kh : (void*)vt;
    gemm_body(A, W, bias, dst, (*flag) != 0, (z < 2) ? 0 : 2,
              blockIdx.y * BM, blockIdx.x * BN, M, N, K);
}

__global__ __launch_bounds__(256) void gemm_out(
    const u16* __restrict__ A, const u16* __restrict__ W,
    const void* __restrict__ bias, void* __restrict__ dst,
    const int* __restrict__ flag, int M, int N, int K)
{
    gemm_body(A, W, bias, dst, (*flag) != 0, 1,
              blockIdx.y * BM, blockIdx.x * BN, M, N, K);
}

// ---------------------------------------------------------------------------
// Fused AKT attention. Grid 8192 (XCD-swizzled), 512 thr.
// Phase 2 is causal W-segmented: W = pow2 lanes covering the block's qmax,
// so a wave processes 64/W rows per pass (up to 8), skipping masked columns
// wave-uniformly. Scan/reduce are width-W shuffles. P + V in f16; phase 3
// uses f16 MFMA.
// ---------------------------------------------------------------------------
#define QT  16
#define SRS 568   // u16 units; row = 1136 B (16B-aligned)
#define PRS 584

__global__ __launch_bounds__(512) void akt_attn(
    const u16* __restrict__ qh, const u16* __restrict__ kh,
    const u16* __restrict__ vt, const _Float16* __restrict__ diff,
    const void* __restrict__ gammas, const int* __restrict__ zero_pad,
    const int* __restrict__ flag, u16* __restrict__ attn)
{
    __shared__ _Float16 s_h[QT * SRS];   // 18176 B (reused as f32 partials ph3)
    __shared__ u16      p_lds[QT * PRS]; // 18688 B (f16 P)

    const int blk = blockIdx.x;
    const int h = blk & 7;               // XCD pin: (b,h) fixed per XCD
    const int i0 = blk >> 3;
    const int qt = i0 & 31;
    const int b = i0 >> 5;

    const int q0 = qt * QT;
    const int t = threadIdx.x, w = t >> 6, l = t & 63;
    const int lq = l & 15, quad = l >> 4;
    const bool f32 = (*flag) != 0;
    const size_t bh = ((size_t)b * 8 + h) * 512;
    const int qmax = q0 + QT - 1;

    // ---------------- phase 1: scores = (qh @ kh^T) * 0.125*log2e -> f16 ----
    {
        const u16* qb = qh + (bh + q0) * 64;
        short8 af0 = *(const short8*)(qb + lq * 64 +      quad * 8);
        short8 af1 = *(const short8*)(qb + lq * 64 + 32 + quad * 8);
        const u16* kb = kh + bh * 64;
        const int KT = (q0 + QT + 127) >> 7;
        int n0 = w * 16;
        bool act = (n0 <= qmax);
        short8 bf0, bf1;
        if (act) {
            bf0 = *(const short8*)(kb + (size_t)(n0 + lq) * 64 +      quad * 8);
            bf1 = *(const short8*)(kb + (size_t)(n0 + lq) * 64 + 32 + quad * 8);
        }
        for (int kt = 0; kt < KT; ++kt) {
            const int n0n = (kt + 1) * 128 + w * 16;
            const bool actn = (kt + 1 < KT) && (n0n <= qmax);
            short8 nb0, nb1;
            if (actn) {
                nb0 = *(const short8*)(kb + (size_t)(n0n + lq) * 64 +      quad * 8);
                nb1 = *(const short8*)(kb + (size_t)(n0n + lq) * 64 + 32 + quad * 8);
            }
            if (act) {
                f32x4 acc = {0.f, 0.f, 0.f, 0.f};
                acc = __builtin_amdgcn_mfma_f32_16x16x32_bf16(af0, bf0, acc, 0, 0, 0);
                acc = __builtin_amdgcn_mfma_f32_16x16x32_bf16(af1, bf1, acc, 0, 0, 0);
                const int cm = n0 + lq + 8 * (n0 >> 6);
                #pragma unroll
                for (int r = 0; r < 4; ++r)
                    s_h[(quad * 4 + r) * SRS + cm] =
                        (_Float16)(acc[r] * 0.180336880f);  // 0.125*log2e
            }
            bf0 = nb0; bf1 = nb1; act = actn; n0 = n0n;
        }
    }
    __syncthreads();

    // ---------------- phase 2: causal W-segmented rescore -------------------
    {
        const float g = ldf(gammas, h, f32);
        const float gl2 = -log1pf(expf(g)) * 1.4426950408889634f; // gamma*log2e
        const int zp = zero_pad[0];
        // segment width: W lanes x 8 cols cover all columns <= qmax
        const int need = (qmax >> 3) + 1;          // lanes of 8 cols needed
        int W = 8; while (W < need) W <<= 1;       // 8,16,32,64
        const int lw = 31 - __builtin_clz(W);
        const int R = 64 >> lw;                    // rows per pass (8,4,2,1)
        const int G = W >> 2;                      // row-groups = 16/R
        const int ln = l & (W - 1);
        const int seg = l >> lw;
        const int c0 = ln * 8;
        const int cm = c0 + 8 * (c0 >> 6);
        for (int p = w; p < G; p += 8) {
            const int row = p * R + seg;
            const int q = q0 + row;
            // precomputed f16 diff prefetch FIRST
            const size_t qoff = ((size_t)b * 512 + q) * 512 + c0;
            h8 dv = *(const h8*)(diff + qoff);
            // staggered f16 score load (16 B, already in log2 domain)
            h8 sv16 = *(const h8*)(s_h + row * SRS + cm);
            float sv[8], cs[8];
            float run = 0.f;
            #pragma unroll
            for (int j = 0; j < 8; ++j) {
                float s = (c0 + j <= q) ? (float)sv16[j] : -1e30f;
                sv[j] = s;
                float pp = ex2(s);                 // softmax #1 numerator
                run += pp; cs[j] = run;
            }
            // width-W inclusive scan of per-lane sums
            float incl = run;
            for (int o = 1; o < W; o <<= 1) {
                float u = __shfl_up(incl, o, W);
                if (ln >= o) incl += u;
            }
            const float ls   = __shfl(incl, W - 1, W);  // segment total
            const float inv1 = __builtin_amdgcn_rcpf(ls);
            const float t0   = ls - incl + run;    // ls - exclusive_prefix
            const float qf   = (float)(q - c0);
            // decay rescore + softmax #2 (disttot == 1 identically)
            float f8[8]; float lf = 0.f;
            #pragma unroll
            for (int j = 0; j < 8; ++j) {
                float suf  = t0 - cs[j];           // suffix sum (unnormalized)
                float pos  = qf - (float)j;
                float m    = fmaxf(suf * pos, 0.f) * inv1;
                float dist = __builtin_amdgcn_sqrtf(m);
                // gamma<0 -> arg<=0; only low clamp binds: arg >= log2(1e-5)
                float a    = fmaxf(dist * gl2 * (float)dv[j], -16.609640474f);
                float eff  = ex2(a);
                // masked: sv=-1e30, eff>=1e-5 -> arg<=-1e25 -> f=0
                float f    = ex2(sv[j] * eff);
                f8[j] = f; lf += f;
            }
            #pragma unroll 6
            for (int o = W >> 1; o > 0; o >>= 1) lf += __shfl_xor(lf, o, 64);
            float inv2 = __builtin_amdgcn_rcpf(lf);
            if (zp && q == 0) inv2 = 0.f;
            h8 pb;
            #pragma unroll
            for (int j = 0; j < 8; ++j) pb[j] = (_Float16)(f8[j] * inv2);
            *(h8*)((_Float16*)p_lds + row * PRS + cm) = pb;
        }
    }
    __syncthreads();

    // ---------------- phase 3: O = P @ V (f16 MFMA), 8 waves (k-halves) -----
    {
        const int g = w & 3;                 // output 16-col group
        const int half = w >> 2;             // k-chunk parity
        const int KS = (qmax >> 5) + 1;
        const _Float16* vb = (const _Float16*)vt +
            ((size_t)(b * 8 + h) * 64 + g * 16 + lq) * 512;
        const _Float16* prow = (const _Float16*)p_lds + lq * PRS;
        f32x4 oacc = {0.f, 0.f, 0.f, 0.f};
        for (int ks = half; ks < KS; ks += 2) {
            const int kb2 = ks * 32 + quad * 8;
            h8 pa = *(const h8*)(prow + kb2 + 8 * (kb2 >> 6));
            h8 vv = *(const h8*)(vb + kb2);
            oacc = __builtin_amdgcn_mfma_f32_16x16x32_f16(pa, vv, oacc, 0, 0, 0);
        }
        float* opart = (float*)s_h;          // reuse score LDS (post-barrier)
        if (half == 1) {
            #pragma unroll
            for (int r = 0; r < 4; ++r)
                opart[(g * 16 + quad * 4 + r) * 17 + lq] = oacc[r];
        }
        __syncthreads();
        if (half == 0) {
            const size_t ob = ((size_t)b * 512 + q0 + quad * 4) * 512 + h * 64 + g * 16 + lq;
            #pragma unroll
            for (int r = 0; r < 4; ++r)
                attn[ob + (size_t)r * 512] =
                    f2b(oacc[r] + opart[(g * 16 + quad * 4 + r) * 17 + lq]);
        }
    }
}

// ---------------------------------------------------------------------------
extern "C" void kernel_launch(void* const* d_in, const int* in_sizes, int n_in,
                              void* d_out, int out_size, void* d_ws, size_t ws_size,
                              hipStream_t stream) {
    const void* q   = d_in[0];
    const void* k   = d_in[1];
    const void* v   = d_in[2];
    // d_in[3] = mask (tril) == (k<=q), unused
    const int*  zp  = (const int*)d_in[4];
    const void* qde = d_in[5];
    const void* Wk  = d_in[6];
    const void* bk  = d_in[7];
    const void* Wv  = d_in[8];
    const void* bv  = d_in[9];
    const void* Wo  = d_in[10];
    const void* bo  = d_in[11];
    const void* gam = d_in[12];

    const int M = 32 * 512, N = 512, K = 512;
    const int NBIG = M * K;        // 8388608
    const int NW = 512 * 512;      // 262144

    char* ws = (char*)d_ws;
    int* flag = (int*)ws;
    const size_t SZB = (size_t)NBIG * 2;   // 16.8 MB
    const size_t SZW = (size_t)NW * 2;     // 0.5 MB
    u16* cWk  = (u16*)(ws + 1024);
    u16* cWv  = (u16*)(ws + 1024 + SZW);
    u16* cWo  = (u16*)(ws + 1024 + 2 * SZW);
    u16* cq   = (u16*)(ws + 1024 + 3 * SZW);
    u16* ck   = (u16*)(ws + 1024 + 3 * SZW + SZB);
    u16* cv   = (u16*)(ws + 1024 + 3 * SZW + 2 * SZB);
    u16* qh   = (u16*)(ws + 1024 + 3 * SZW + 3 * SZB);
    u16* kh   = (u16*)(ws + 1024 + 3 * SZW + 4 * SZB);
    u16* vt   = (u16*)(ws + 1024 + 3 * SZW + 5 * SZB);   // [B,H,64,S] f16
    u16* attn = (u16*)(ws + 1024 + 3 * SZW + 6 * SZB);   // [B,S,512] bf16

    detect_f32<<<1, 256, 0, stream>>>((const u16*)q, flag);
    cvt3<<<dim3(NW / 2048, 1, 3), 256, 0, stream>>>(Wk, Wv, Wo, cWk, cWv, cWo, NW, flag);
    cvt3<<<dim3(NBIG / 2048, 1, 3), 256, 0, stream>>>(q, k, v, cq, ck, cv, NBIG, flag);
    proj3<<<dim3(N / BN, M / BM, 3), 256, 0, stream>>>(
        cq, ck, cv, cWk, cWv, bk, bv, qh, kh, vt, flag, M, N, K);
    // cq dead after proj3 -> reuse its slot for f16 diff = exp(sigmoid(qde))
    _Float16* diffb = (_Float16*)cq;
    prep_diff<<<dim3(NBIG / 2048), 256, 0, stream>>>(qde, diffb, NBIG, flag);
    akt_attn<<<8192, 512, 0, stream>>>(qh, kh, vt, diffb, gam, zp, flag, attn);
    gemm_out<<<dim3(N / BN, M / BM), 256, 0, stream>>>(attn, cWo, bo, d_out, flag, M, N, K);
}